// Round 11
// baseline (1011.139 us; speedup 1.0000x reference)
//
#include <hip/hip_runtime.h>
#include <math.h>

// Problem dims
#define B_ 4
#define L_ 512
#define MROWS 2048
#define D_MODEL 384
#define N_LAYER 4
#define D_INNER 768
#define N_STATE 16
#define DT_RANK 24
#define D_CONV 4
#define VOCAB 1544
#define FEAT 1536
#define XPROJ_N 56
#define NCH 8               // scan chunks per batch (L/64)
#define SCH 64              // scan chunk length

typedef __attribute__((ext_vector_type(8))) short short8;
typedef __attribute__((ext_vector_type(4))) float floatx4;

__device__ __forceinline__ float softplus_f(float x) { return x > 20.f ? x : log1pf(expf(x)); }
__device__ __forceinline__ float silu_f(float x) { return x / (1.f + __expf(-x)); }

// f32 -> bf16 (RNE), two packed into one u32
__device__ __forceinline__ unsigned pack2bf(float x, float y) {
    unsigned ux = __float_as_uint(x); ux = (ux + 0x7FFFu + ((ux >> 16) & 1u)) >> 16;
    unsigned uy = __float_as_uint(y); uy = (uy + 0x7FFFu + ((uy >> 16) & 1u)) >> 16;
    return ux | (uy << 16);
}

// DPP row-rotate add: x + (x rotated by N within each 16-lane row).
template <int CTRL>
__device__ __forceinline__ float dpp_radd(float x) {
    int r = __builtin_amdgcn_update_dpp(0, __float_as_int(x), CTRL, 0xf, 0xf, true);
    return x + __int_as_float(r);
}

__device__ __forceinline__ float4 ld4_guard(const float* __restrict__ p, int k, int ke) {
    if (k + 3 < ke) return *(const float4*)(p + k);
    float4 r = make_float4(0.f, 0.f, 0.f, 0.f);
    if (k + 0 < ke) r.x = p[k + 0];
    if (k + 1 < ke) r.y = p[k + 1];
    if (k + 2 < ke) r.z = p[k + 2];
    return r;
}

__device__ __forceinline__ short8 ld8h_guard(const short* __restrict__ p, int k, int ke) {
    if (k + 7 < ke) return *(const short8*)(p + k);
    short8 r = {0, 0, 0, 0, 0, 0, 0, 0};
#pragma unroll
    for (int j = 0; j < 8; ++j)
        if (k + j < ke) r[j] = p[k + j];
    return r;
}

// ---------------------------------------------------------------------------
// One-shot weight cast f32 -> bf16.
// ---------------------------------------------------------------------------
struct CastDesc {
    const float* src[6];
    short*       dst[6];
    unsigned     cum[6];   // exclusive prefix ends, in float4 units
};

__global__ __launch_bounds__(256) void cast_w_k(CastDesc cd, unsigned total4)
{
    unsigned i = blockIdx.x * 256 + threadIdx.x;
    if (i >= total4) return;
    int s = 0;
#pragma unroll
    for (int j = 0; j < 5; ++j)
        if (i >= cd.cum[j] && s == j) s = j + 1;
    unsigned off = i - (s ? cd.cum[s - 1] : 0u);
    float4 v = ((const float4*)cd.src[s])[off];
    uint2 pk;
    pk.x = pack2bf(v.x, v.y);
    pk.y = pack2bf(v.z, v.w);
    ((uint2*)cd.dst[s])[off] = pk;
}

// ---------------------------------------------------------------------------
// MFMA bf16 GEMM: C[m,n] (+)= sum_k A[m,k]*W[n,k].  W pre-cast bf16.
// Pipelined: stage(k+1) -> prefetch(k+2) -> MFMA(k) -> barrier (r10: -48us).
// ABF: A pre-cast bf16. EPI: 0 none, 1 +bias(z==0 if ATOMIC), 2 softplus+bias.
// ---------------------------------------------------------------------------
#define ASTR 40

template <int EPI, bool GATED, bool ATOMIC, bool RMSN, bool NG, bool ABF>
__global__ __launch_bounds__(256) void mfma_gemm(
    const float* __restrict__ A, const short* __restrict__ Abf,
    const short* __restrict__ Wb,
    const float* __restrict__ bias, const float* __restrict__ gate,
    const float* __restrict__ nw,
    float* __restrict__ C, int M, int N, int K, int lda, int ldg, int ldc, int KC)
{
    __shared__ short As[2][64 * ASTR];
    __shared__ short Ws[2][64 * ASTR];
    __shared__ float sscale[64];

    const int t  = threadIdx.x;
    const int m0 = blockIdx.y * 64;
    const int n0 = blockIdx.x * 64;
    const int ks = blockIdx.z * KC;
    const int ke = min(K, ks + KC);

    const int srow = t >> 2;           // 0..63
    const int sseg = (t & 3) * 8;      // 0,8,16,24

    if (RMSN) {
        const int row = t >> 2, q = t & 3;
        const float* xr = A + (size_t)(m0 + row) * lda + q * (K >> 2);
        float s = 0.f;
        for (int i = 0; i < (K >> 2); i += 4) {
            float4 v = *(const float4*)(xr + i);
            s += v.x * v.x + v.y * v.y + v.z * v.z + v.w * v.w;
        }
        s += __shfl_xor(s, 1, 64);
        s += __shfl_xor(s, 2, 64);
        if (q == 0) sscale[row] = rsqrtf(s / (float)K + 1e-5f);
        __syncthreads();
    }

    float4 ra0, ra1, rg0, rg1, rn0, rn1;
    short8 ra8, rw8;

    auto prefetch = [&](int k0) {
        if (ABF) {
            ra8 = ld8h_guard(Abf + (size_t)(m0 + srow) * lda, k0 + sseg, ke);
        } else {
            const float* ar = A + (size_t)(m0 + srow) * lda;
            ra0 = ld4_guard(ar, k0 + sseg, ke);
            ra1 = ld4_guard(ar, k0 + sseg + 4, ke);
            if (GATED) {
                const float* gr = gate + (size_t)(m0 + srow) * ldg;
                rg0 = ld4_guard(gr, k0 + sseg, ke);
                rg1 = ld4_guard(gr, k0 + sseg + 4, ke);
            }
            if (RMSN) {
                rn0 = ld4_guard(nw, k0 + sseg, ke);
                rn1 = ld4_guard(nw, k0 + sseg + 4, ke);
            }
        }
        if (!NG || (n0 + srow) < N) {
            rw8 = ld8h_guard(Wb + (size_t)(n0 + srow) * (size_t)K, k0 + sseg, ke);
        } else {
            rw8 = (short8){0, 0, 0, 0, 0, 0, 0, 0};
        }
    };

    auto stage = [&](int p) {
        if (ABF) {
            *(short8*)&As[p][srow * ASTR + sseg] = ra8;
        } else {
            float4 a0 = ra0, a1 = ra1;
            if (GATED) {
                a0.x *= silu_f(rg0.x); a0.y *= silu_f(rg0.y); a0.z *= silu_f(rg0.z); a0.w *= silu_f(rg0.w);
                a1.x *= silu_f(rg1.x); a1.y *= silu_f(rg1.y); a1.z *= silu_f(rg1.z); a1.w *= silu_f(rg1.w);
            }
            if (RMSN) {
                float sc = sscale[srow];
                a0.x *= sc * rn0.x; a0.y *= sc * rn0.y; a0.z *= sc * rn0.z; a0.w *= sc * rn0.w;
                a1.x *= sc * rn1.x; a1.y *= sc * rn1.y; a1.z *= sc * rn1.z; a1.w *= sc * rn1.w;
            }
            int4 pa;
            pa.x = pack2bf(a0.x, a0.y); pa.y = pack2bf(a0.z, a0.w);
            pa.z = pack2bf(a1.x, a1.y); pa.w = pack2bf(a1.z, a1.w);
            *(int4*)&As[p][srow * ASTR + sseg] = pa;
        }
        *(short8*)&Ws[p][srow * ASTR + sseg] = rw8;
    };

    prefetch(ks);
    stage(0);
    if (ks + 32 < ke) prefetch(ks + 32);   // loads for iter 2 in flight across barrier
    __syncthreads();

    floatx4 acc[2][2];
#pragma unroll
    for (int i = 0; i < 2; ++i)
#pragma unroll
        for (int j = 0; j < 2; ++j) acc[i][j] = (floatx4){0.f, 0.f, 0.f, 0.f};

    const int w    = t >> 6;
    const int lane = t & 63;
    const int quad = lane >> 4;
    const int lm   = lane & 15;
    const int aoff = ((w >> 1) * 32 + lm) * ASTR + quad * 8;
    const int boff = ((w & 1) * 32 + lm) * ASTR + quad * 8;

    int p = 0;
    for (int k0 = ks; k0 < ke; k0 += 32) {
        const bool more = (k0 + 32 < ke);
        if (more) {
            stage(p ^ 1);                        // consumes loads issued 1 iter ago
            if (k0 + 64 < ke) prefetch(k0 + 64); // issue 2 iters ahead
        }
        short8 a0 = *(const short8*)&As[p][aoff];
        short8 a1 = *(const short8*)&As[p][aoff + 16 * ASTR];
        short8 b0 = *(const short8*)&Ws[p][boff];
        short8 b1 = *(const short8*)&Ws[p][boff + 16 * ASTR];
        acc[0][0] = __builtin_amdgcn_mfma_f32_16x16x32_bf16(a0, b0, acc[0][0], 0, 0, 0);
        acc[0][1] = __builtin_amdgcn_mfma_f32_16x16x32_bf16(a0, b1, acc[0][1], 0, 0, 0);
        acc[1][0] = __builtin_amdgcn_mfma_f32_16x16x32_bf16(a1, b0, acc[1][0], 0, 0, 0);
        acc[1][1] = __builtin_amdgcn_mfma_f32_16x16x32_bf16(a1, b1, acc[1][1], 0, 0, 0);
        if (more) {
            __syncthreads();
            p ^= 1;
        }
    }

    const int rbase = m0 + (w >> 1) * 32 + quad * 4;
    const int cbase = n0 + (w & 1) * 32 + lm;
#pragma unroll
    for (int mt = 0; mt < 2; ++mt)
#pragma unroll
        for (int nt = 0; nt < 2; ++nt) {
            const int gc = cbase + nt * 16;
            if (NG && gc >= N) continue;
#pragma unroll
            for (int r = 0; r < 4; ++r) {
                const size_t gr = rbase + mt * 16 + r;
                float v = acc[mt][nt][r];
                if (ATOMIC) {
                    if (EPI == 1 && blockIdx.z == 0) v += bias[gc];
                    atomicAdd(&C[gr * ldc + gc], v);
                } else {
                    if (EPI == 1) v += bias[gc];
                    if (EPI == 2) v = softplus_f(v + bias[gc]);
                    C[gr * ldc + gc] = v;
                }
            }
        }
}

// ---------------------------------------------------------------------------
// Depthwise causal conv (width 4) + bias + SiLU; writes u (f32) and u_bf.
// ---------------------------------------------------------------------------
__global__ __launch_bounds__(256) void conv_silu_k(
    const float* __restrict__ xz, const float* __restrict__ w,
    const float* __restrict__ cb, float* __restrict__ u, short* __restrict__ ubf)
{
    int idx = blockIdx.x * 256 + threadIdx.x;
    if (idx >= MROWS * (D_INNER / 4)) return;
    int dq = idx % (D_INNER / 4);
    int m  = idx / (D_INNER / 4);
    int d0 = dq * 4;
    int b = m / L_, l = m % L_;
    float4 wq[4];
#pragma unroll
    for (int j = 0; j < 4; ++j) wq[j] = *(const float4*)(w + (d0 + j) * D_CONV);
    float acc[4];
#pragma unroll
    for (int j = 0; j < 4; ++j) acc[j] = cb[d0 + j];
#pragma unroll
    for (int tt = 0; tt < 4; ++tt) {
        int ll = l - 3 + tt;
        if (ll >= 0) {
            float4 xv = *(const float4*)(xz + (size_t)(b * L_ + ll) * (2 * D_INNER) + d0);
            acc[0] = fmaf(xv.x, ((const float*)&wq[0])[tt], acc[0]);
            acc[1] = fmaf(xv.y, ((const float*)&wq[1])[tt], acc[1]);
            acc[2] = fmaf(xv.z, ((const float*)&wq[2])[tt], acc[2]);
            acc[3] = fmaf(xv.w, ((const float*)&wq[3])[tt], acc[3]);
        }
    }
    float4 o = make_float4(silu_f(acc[0]), silu_f(acc[1]), silu_f(acc[2]), silu_f(acc[3]));
    *(float4*)(u + (size_t)m * D_INNER + d0) = o;
    uint2 pk;
    pk.x = pack2bf(o.x, o.y);
    pk.y = pack2bf(o.z, o.w);
    *(uint2*)(ubf + (size_t)m * D_INNER + d0) = pk;
}

// ---------------------------------------------------------------------------
// Fused chunked selective scan (single dispatch, decoupled lookback).
// grid (48, NCH, B_), block 256 = 16 d x 16 n.  All 1536 blocks co-resident
// (LDS 20KB -> 8 blocks/CU >= 6 needed), so flag spin cannot deadlock.
// Chunk c: local scan into sy (LDS) -> publish (P,H) + flag=layer+1 ->
// (c>0) spin on flags 0..c-1, fold h_start, re-walk adding carry -> y once.
// Flags never memset: poison 0xAAAAAAAA != 1..4, prior layer value != layer+1.
// ---------------------------------------------------------------------------
__global__ __launch_bounds__(256) void scan_k(
    const float* __restrict__ delta, const float* __restrict__ u,
    const float* __restrict__ xdbl, const float* __restrict__ A_log,
    const float* __restrict__ Dp, float* __restrict__ y,
    float* __restrict__ Pws, float* __restrict__ Hws,
    int* __restrict__ flags, int layer)
{
    __shared__ float sd[SCH][16], su[SCH][16], sB[SCH][16], sC[SCH][16], sy[SCH][16];
    const int t  = threadIdx.x;
    const int n  = t & 15;
    const int dl = t >> 4;
    const int dg = blockIdx.x;
    const int c  = blockIdx.y;
    const int b  = blockIdx.z;
    const int d  = dg * 16 + dl;
    const int l0 = c * SCH;

    const float Av = -expf(A_log[d * N_STATE + n]);
    const float Dd = Dp[d];
    const int lr = t >> 2;
    const int lc = (t & 3) << 2;

    {
        const size_t mrow = (size_t)b * L_ + l0 + lr;
        *(float4*)&sd[lr][lc] = *(const float4*)(delta + mrow * D_INNER + dg * 16 + lc);
        *(float4*)&su[lr][lc] = *(const float4*)(u     + mrow * D_INNER + dg * 16 + lc);
        *(float4*)&sB[lr][lc] = *(const float4*)(xdbl  + mrow * XPROJ_N + DT_RANK + lc);
        *(float4*)&sC[lr][lc] = *(const float4*)(xdbl  + mrow * XPROJ_N + DT_RANK + N_STATE + lc);
    }
    __syncthreads();

    // pass 1: local scan (h0 = 0)
    float h = 0.f, pacc = 1.f;
#pragma unroll 8
    for (int j = 0; j < SCH; ++j) {
        float dv = sd[j][dl];
        float uv = su[j][dl];
        float e  = __expf(dv * Av);
        float cc = dv * uv * sB[j][n];
        h = fmaf(e, h, cc);
        pacc *= e;
        float p = h * sC[j][n];
        p = dpp_radd<0x128>(p);
        p = dpp_radd<0x124>(p);
        p = dpp_radd<0x122>(p);
        p = dpp_radd<0x121>(p);
        if (n == 0) sy[j][dl] = fmaf(uv, Dd, p);
    }

    // publish end-state for downstream chunks
    if (c < NCH - 1) {
        const size_t phi = (((size_t)(b * NCH + c) * D_INNER + d) << 4) + n;
        Pws[phi] = pacc;
        Hws[phi] = h;
        __syncthreads();            // all 256 stores issued
        if (t == 0) {
            __threadfence();        // drain to device scope
            __hip_atomic_store(&flags[b * NCH + c], layer + 1,
                               __ATOMIC_RELEASE, __HIP_MEMORY_SCOPE_AGENT);
        }
    }

    // pass 2: carry-in correction
    if (c > 0) {
        if (t < c) {
            while (__hip_atomic_load(&flags[b * NCH + t],
                                     __ATOMIC_ACQUIRE, __HIP_MEMORY_SCOPE_AGENT)
                   != layer + 1) { }
        }
        __syncthreads();
        float hs = 0.f;
        for (int s = 0; s < c; ++s) {
            const size_t phi = (((size_t)(b * NCH + s) * D_INNER + d) << 4) + n;
            hs = fmaf(Pws[phi], hs, Hws[phi]);
        }
        float g = hs;
#pragma unroll 8
        for (int j = 0; j < SCH; ++j) {
            g *= __expf(sd[j][dl] * Av);
            float p = g * sC[j][n];
            p = dpp_radd<0x128>(p);
            p = dpp_radd<0x124>(p);
            p = dpp_radd<0x122>(p);
            p = dpp_radd<0x121>(p);
            if (n == 0) sy[j][dl] += p;
        }
    }

    __syncthreads();
    {
        const size_t mrow = (size_t)b * L_ + l0 + lr;
        *(float4*)(y + mrow * D_INNER + dg * 16 + lc) = *(const float4*)&sy[lr][lc];
    }
}

// ---------------------------------------------------------------------------
extern "C" void kernel_launch(void* const* d_in, const int* in_sizes, int n_in,
                              void* d_out, int out_size, void* d_ws, size_t ws_size,
                              hipStream_t stream)
{
    const float* input_ids = (const float*)d_in[0];
    const float* fc_W      = (const float*)d_in[1];
    const float* fc_b      = (const float*)d_in[2];
    const float* in_proj_W = (const float*)d_in[3];
    const float* conv_W    = (const float*)d_in[4];
    const float* conv_b    = (const float*)d_in[5];
    const float* x_proj_W  = (const float*)d_in[6];
    const float* dt_proj_W = (const float*)d_in[7];
    const float* dt_proj_b = (const float*)d_in[8];
    const float* A_log     = (const float*)d_in[9];
    const float* Dp        = (const float*)d_in[10];
    const float* out_proj_W= (const float*)d_in[11];
    const float* norm_W    = (const float*)d_in[12];
    const float* normf_W   = (const float*)d_in[13];
    const float* head_W    = (const float*)d_in[14];
    float* out = (float*)d_out;

    float* ws       = (float*)d_ws;
    float* x_ws     = ws;                                    // M*384
    float* xz_ws    = x_ws    + (size_t)MROWS * D_MODEL;     // M*1536
    float* u_ws     = xz_ws   + (size_t)MROWS * 2 * D_INNER; // M*768
    float* xdbl_ws  = u_ws    + (size_t)MROWS * D_INNER;     // M*56
    float* delta_ws = xdbl_ws + (size_t)MROWS * XPROJ_N;     // M*768
    float* y_ws     = delta_ws+ (size_t)MROWS * D_INNER;     // M*768
    float* P_ws     = y_ws    + (size_t)MROWS * D_INNER;     // B*8*768*16
    float* H_ws     = P_ws    + (size_t)B_ * NCH * D_INNER * N_STATE;
    int*   flags_ws = (int*)(H_ws + (size_t)B_ * NCH * D_INNER * N_STATE); // 32 ints
    short* bf       = (short*)(flags_ws + 64);               // keep 16B alignment
    short* wbf_fc   = bf;
    short* wbf_in   = wbf_fc  + (size_t)D_MODEL * VOCAB;
    short* wbf_x    = wbf_in  + (size_t)N_LAYER * 2 * D_INNER * D_MODEL;
    short* wbf_dt   = wbf_x   + (size_t)N_LAYER * XPROJ_N * D_INNER;
    short* wbf_out  = wbf_dt  + (size_t)N_LAYER * D_INNER * DT_RANK;
    short* wbf_head = wbf_out + (size_t)N_LAYER * D_MODEL * D_INNER;
    short* ubf_ws   = wbf_head+ (size_t)FEAT * D_MODEL;

    const dim3 blk(256);

    // --- one-shot weight cast to bf16 ---
    CastDesc cd;
    cd.src[0] = fc_W;       cd.dst[0] = wbf_fc;
    cd.src[1] = in_proj_W;  cd.dst[1] = wbf_in;
    cd.src[2] = x_proj_W;   cd.dst[2] = wbf_x;
    cd.src[3] = dt_proj_W;  cd.dst[3] = wbf_dt;
    cd.src[4] = out_proj_W; cd.dst[4] = wbf_out;
    cd.src[5] = head_W;     cd.dst[5] = wbf_head;
    unsigned c0 = (unsigned)(D_MODEL * VOCAB / 4);
    unsigned c1 = c0 + (unsigned)(N_LAYER * 2 * D_INNER * D_MODEL / 4);
    unsigned c2 = c1 + (unsigned)(N_LAYER * XPROJ_N * D_INNER / 4);
    unsigned c3 = c2 + (unsigned)(N_LAYER * D_INNER * DT_RANK / 4);
    unsigned c4 = c3 + (unsigned)(N_LAYER * D_MODEL * D_INNER / 4);
    unsigned c5 = c4 + (unsigned)(FEAT * D_MODEL / 4);
    cd.cum[0] = c0; cd.cum[1] = c1; cd.cum[2] = c2;
    cd.cum[3] = c3; cd.cum[4] = c4; cd.cum[5] = c5;
    cast_w_k<<<(c5 + 255) / 256, blk, 0, stream>>>(cd, c5);

    // x = input_ids @ fc_W.T + fc_b   (split-K=7, KC=256)
    hipMemsetAsync(x_ws, 0, (size_t)MROWS * D_MODEL * sizeof(float), stream);
    mfma_gemm<1, false, true, false, false, false><<<dim3(D_MODEL / 64, MROWS / 64, 7), blk, 0, stream>>>(
        input_ids, nullptr, wbf_fc, fc_b, nullptr, nullptr, x_ws,
        MROWS, D_MODEL, VOCAB, VOCAB, 0, D_MODEL, 256);

    for (int i = 0; i < N_LAYER; ++i) {
        // xz = rmsnorm(x, norm_W) @ in_proj_W.T   (rmsnorm fused into A staging)
        mfma_gemm<0, false, false, true, false, false><<<dim3(2 * D_INNER / 64, MROWS / 64, 1), blk, 0, stream>>>(
            x_ws, nullptr, wbf_in + (size_t)i * 2 * D_INNER * D_MODEL,
            nullptr, nullptr, norm_W + i * D_MODEL, xz_ws,
            MROWS, 2 * D_INNER, D_MODEL, D_MODEL, 0, 2 * D_INNER, D_MODEL);

        // u = silu(conv(xz[:, :768]) + conv_b)  (f32 + bf16 copies)
        conv_silu_k<<<(MROWS * (D_INNER / 4) + 255) / 256, blk, 0, stream>>>(
            xz_ws, conv_W + (size_t)i * D_INNER * D_CONV, conv_b + i * D_INNER,
            u_ws, ubf_ws);

        // x_dbl = u @ x_proj_W[i].T  (split-K=12 -> 384 blocks; was 6/192: 0.75/CU)
        hipMemsetAsync(xdbl_ws, 0, (size_t)MROWS * XPROJ_N * sizeof(float), stream);
        mfma_gemm<0, false, true, false, true, true><<<dim3(1, MROWS / 64, 12), blk, 0, stream>>>(
            nullptr, ubf_ws, wbf_x + (size_t)i * XPROJ_N * D_INNER,
            nullptr, nullptr, nullptr, xdbl_ws,
            MROWS, XPROJ_N, D_INNER, D_INNER, 0, XPROJ_N, 64);

        // delta = softplus(x_dbl[:, :24] @ dt_proj_W[i].T + dt_proj_b[i])  (1 k-iter)
        mfma_gemm<2, false, false, false, false, false><<<dim3(D_INNER / 64, MROWS / 64, 1), blk, 0, stream>>>(
            xdbl_ws, nullptr, wbf_dt + (size_t)i * D_INNER * DT_RANK,
            dt_proj_b + i * D_INNER, nullptr, nullptr, delta_ws,
            MROWS, D_INNER, DT_RANK, XPROJ_N, 0, D_INNER, DT_RANK);

        // fused chunked selective scan (single dispatch)
        scan_k<<<dim3(D_INNER / 16, NCH, B_), blk, 0, stream>>>(
            delta_ws, u_ws, xdbl_ws, A_log + (size_t)i * D_INNER * N_STATE,
            Dp + i * D_INNER, y_ws, P_ws, H_ws, flags_ws, i);

        // x += (y * silu(res)) @ out_proj_W.T  (gated A, split-K=3, atomic residual)
        mfma_gemm<0, true, true, false, false, false><<<dim3(D_MODEL / 64, MROWS / 64, 3), blk, 0, stream>>>(
            y_ws, nullptr, wbf_out + (size_t)i * D_MODEL * D_INNER,
            nullptr, xz_ws + D_INNER, nullptr, x_ws,
            MROWS, D_MODEL, D_INNER, D_INNER, 2 * D_INNER, D_MODEL, 256);
    }

    // out = rmsnorm(x, normf_W) @ head_W.T  (rmsnorm fused)
    mfma_gemm<0, false, false, true, false, false><<<dim3(FEAT / 64, MROWS / 64, 1), blk, 0, stream>>>(
        x_ws, nullptr, wbf_head, nullptr, nullptr, normf_W, out,
        MROWS, FEAT, D_MODEL, D_MODEL, 0, FEAT, D_MODEL);
}

// Round 12
// 688.620 us; speedup vs baseline: 1.4684x; 1.4684x over previous
//
#include <hip/hip_runtime.h>
#include <math.h>

// Problem dims
#define B_ 4
#define L_ 512
#define MROWS 2048
#define D_MODEL 384
#define N_LAYER 4
#define D_INNER 768
#define N_STATE 16
#define DT_RANK 24
#define D_CONV 4
#define VOCAB 1544
#define FEAT 1536
#define XPROJ_N 56
#define NCH 8               // scan chunks per batch (L/64)
#define SCH 64              // scan chunk length

typedef __attribute__((ext_vector_type(8))) short short8;
typedef __attribute__((ext_vector_type(4))) float floatx4;

__device__ __forceinline__ float softplus_f(float x) { return x > 20.f ? x : log1pf(expf(x)); }
__device__ __forceinline__ float silu_f(float x) { return x / (1.f + __expf(-x)); }

// f32 -> bf16 (RNE), two packed into one u32
__device__ __forceinline__ unsigned pack2bf(float x, float y) {
    unsigned ux = __float_as_uint(x); ux = (ux + 0x7FFFu + ((ux >> 16) & 1u)) >> 16;
    unsigned uy = __float_as_uint(y); uy = (uy + 0x7FFFu + ((uy >> 16) & 1u)) >> 16;
    return ux | (uy << 16);
}

// DPP row-rotate add: x + (x rotated by N within each 16-lane row).
template <int CTRL>
__device__ __forceinline__ float dpp_radd(float x) {
    int r = __builtin_amdgcn_update_dpp(0, __float_as_int(x), CTRL, 0xf, 0xf, true);
    return x + __int_as_float(r);
}

__device__ __forceinline__ float4 ld4_guard(const float* __restrict__ p, int k, int ke) {
    if (k + 3 < ke) return *(const float4*)(p + k);
    float4 r = make_float4(0.f, 0.f, 0.f, 0.f);
    if (k + 0 < ke) r.x = p[k + 0];
    if (k + 1 < ke) r.y = p[k + 1];
    if (k + 2 < ke) r.z = p[k + 2];
    return r;
}

__device__ __forceinline__ short8 ld8h_guard(const short* __restrict__ p, int k, int ke) {
    if (k + 7 < ke) return *(const short8*)(p + k);
    short8 r = {0, 0, 0, 0, 0, 0, 0, 0};
#pragma unroll
    for (int j = 0; j < 8; ++j)
        if (k + j < ke) r[j] = p[k + j];
    return r;
}

// ---------------------------------------------------------------------------
// One-shot weight cast f32 -> bf16.
// ---------------------------------------------------------------------------
struct CastDesc {
    const float* src[6];
    short*       dst[6];
    unsigned     cum[6];   // exclusive prefix ends, in float4 units
};

__global__ __launch_bounds__(256) void cast_w_k(CastDesc cd, unsigned total4)
{
    unsigned i = blockIdx.x * 256 + threadIdx.x;
    if (i >= total4) return;
    int s = 0;
#pragma unroll
    for (int j = 0; j < 5; ++j)
        if (i >= cd.cum[j] && s == j) s = j + 1;
    unsigned off = i - (s ? cd.cum[s - 1] : 0u);
    float4 v = ((const float4*)cd.src[s])[off];
    uint2 pk;
    pk.x = pack2bf(v.x, v.y);
    pk.y = pack2bf(v.z, v.w);
    ((uint2*)cd.dst[s])[off] = pk;
}

// ---------------------------------------------------------------------------
// MFMA bf16 GEMM: C[m,n] (+)= sum_k A[m,k]*W[n,k].  W pre-cast bf16.
// Pipelined: stage(k+1) -> prefetch(k+2) -> MFMA(k) -> barrier (r10: -48us).
// ABF: A pre-cast bf16. EPI: 0 none, 1 +bias(z==0 if ATOMIC), 2 softplus+bias.
// NOTE (r11): single-dispatch lookback scan regressed 10x — inter-block
// producer/consumer sync across XCDs costs far more than a kernel boundary.
// ---------------------------------------------------------------------------
#define ASTR 40

template <int EPI, bool GATED, bool ATOMIC, bool RMSN, bool NG, bool ABF>
__global__ __launch_bounds__(256) void mfma_gemm(
    const float* __restrict__ A, const short* __restrict__ Abf,
    const short* __restrict__ Wb,
    const float* __restrict__ bias, const float* __restrict__ gate,
    const float* __restrict__ nw,
    float* __restrict__ C, int M, int N, int K, int lda, int ldg, int ldc, int KC)
{
    __shared__ short As[2][64 * ASTR];
    __shared__ short Ws[2][64 * ASTR];
    __shared__ float sscale[64];

    const int t  = threadIdx.x;
    const int m0 = blockIdx.y * 64;
    const int n0 = blockIdx.x * 64;
    const int ks = blockIdx.z * KC;
    const int ke = min(K, ks + KC);

    const int srow = t >> 2;           // 0..63
    const int sseg = (t & 3) * 8;      // 0,8,16,24

    if (RMSN) {
        const int row = t >> 2, q = t & 3;
        const float* xr = A + (size_t)(m0 + row) * lda + q * (K >> 2);
        float s = 0.f;
        for (int i = 0; i < (K >> 2); i += 4) {
            float4 v = *(const float4*)(xr + i);
            s += v.x * v.x + v.y * v.y + v.z * v.z + v.w * v.w;
        }
        s += __shfl_xor(s, 1, 64);
        s += __shfl_xor(s, 2, 64);
        if (q == 0) sscale[row] = rsqrtf(s / (float)K + 1e-5f);
        __syncthreads();
    }

    float4 ra0, ra1, rg0, rg1, rn0, rn1;
    short8 ra8, rw8;

    auto prefetch = [&](int k0) {
        if (ABF) {
            ra8 = ld8h_guard(Abf + (size_t)(m0 + srow) * lda, k0 + sseg, ke);
        } else {
            const float* ar = A + (size_t)(m0 + srow) * lda;
            ra0 = ld4_guard(ar, k0 + sseg, ke);
            ra1 = ld4_guard(ar, k0 + sseg + 4, ke);
            if (GATED) {
                const float* gr = gate + (size_t)(m0 + srow) * ldg;
                rg0 = ld4_guard(gr, k0 + sseg, ke);
                rg1 = ld4_guard(gr, k0 + sseg + 4, ke);
            }
            if (RMSN) {
                rn0 = ld4_guard(nw, k0 + sseg, ke);
                rn1 = ld4_guard(nw, k0 + sseg + 4, ke);
            }
        }
        if (!NG || (n0 + srow) < N) {
            rw8 = ld8h_guard(Wb + (size_t)(n0 + srow) * (size_t)K, k0 + sseg, ke);
        } else {
            rw8 = (short8){0, 0, 0, 0, 0, 0, 0, 0};
        }
    };

    auto stage = [&](int p) {
        if (ABF) {
            *(short8*)&As[p][srow * ASTR + sseg] = ra8;
        } else {
            float4 a0 = ra0, a1 = ra1;
            if (GATED) {
                a0.x *= silu_f(rg0.x); a0.y *= silu_f(rg0.y); a0.z *= silu_f(rg0.z); a0.w *= silu_f(rg0.w);
                a1.x *= silu_f(rg1.x); a1.y *= silu_f(rg1.y); a1.z *= silu_f(rg1.z); a1.w *= silu_f(rg1.w);
            }
            if (RMSN) {
                float sc = sscale[srow];
                a0.x *= sc * rn0.x; a0.y *= sc * rn0.y; a0.z *= sc * rn0.z; a0.w *= sc * rn0.w;
                a1.x *= sc * rn1.x; a1.y *= sc * rn1.y; a1.z *= sc * rn1.z; a1.w *= sc * rn1.w;
            }
            int4 pa;
            pa.x = pack2bf(a0.x, a0.y); pa.y = pack2bf(a0.z, a0.w);
            pa.z = pack2bf(a1.x, a1.y); pa.w = pack2bf(a1.z, a1.w);
            *(int4*)&As[p][srow * ASTR + sseg] = pa;
        }
        *(short8*)&Ws[p][srow * ASTR + sseg] = rw8;
    };

    prefetch(ks);
    stage(0);
    if (ks + 32 < ke) prefetch(ks + 32);   // loads for iter 2 in flight across barrier
    __syncthreads();

    floatx4 acc[2][2];
#pragma unroll
    for (int i = 0; i < 2; ++i)
#pragma unroll
        for (int j = 0; j < 2; ++j) acc[i][j] = (floatx4){0.f, 0.f, 0.f, 0.f};

    const int w    = t >> 6;
    const int lane = t & 63;
    const int quad = lane >> 4;
    const int lm   = lane & 15;
    const int aoff = ((w >> 1) * 32 + lm) * ASTR + quad * 8;
    const int boff = ((w & 1) * 32 + lm) * ASTR + quad * 8;

    int p = 0;
    for (int k0 = ks; k0 < ke; k0 += 32) {
        const bool more = (k0 + 32 < ke);
        if (more) {
            stage(p ^ 1);                        // consumes loads issued 1 iter ago
            if (k0 + 64 < ke) prefetch(k0 + 64); // issue 2 iters ahead
        }
        short8 a0 = *(const short8*)&As[p][aoff];
        short8 a1 = *(const short8*)&As[p][aoff + 16 * ASTR];
        short8 b0 = *(const short8*)&Ws[p][boff];
        short8 b1 = *(const short8*)&Ws[p][boff + 16 * ASTR];
        acc[0][0] = __builtin_amdgcn_mfma_f32_16x16x32_bf16(a0, b0, acc[0][0], 0, 0, 0);
        acc[0][1] = __builtin_amdgcn_mfma_f32_16x16x32_bf16(a0, b1, acc[0][1], 0, 0, 0);
        acc[1][0] = __builtin_amdgcn_mfma_f32_16x16x32_bf16(a1, b0, acc[1][0], 0, 0, 0);
        acc[1][1] = __builtin_amdgcn_mfma_f32_16x16x32_bf16(a1, b1, acc[1][1], 0, 0, 0);
        if (more) {
            __syncthreads();
            p ^= 1;
        }
    }

    const int rbase = m0 + (w >> 1) * 32 + quad * 4;
    const int cbase = n0 + (w & 1) * 32 + lm;
#pragma unroll
    for (int mt = 0; mt < 2; ++mt)
#pragma unroll
        for (int nt = 0; nt < 2; ++nt) {
            const int gc = cbase + nt * 16;
            if (NG && gc >= N) continue;
#pragma unroll
            for (int r = 0; r < 4; ++r) {
                const size_t gr = rbase + mt * 16 + r;
                float v = acc[mt][nt][r];
                if (ATOMIC) {
                    if (EPI == 1 && blockIdx.z == 0) v += bias[gc];
                    atomicAdd(&C[gr * ldc + gc], v);
                } else {
                    if (EPI == 1) v += bias[gc];
                    if (EPI == 2) v = softplus_f(v + bias[gc]);
                    C[gr * ldc + gc] = v;
                }
            }
        }
}

// ---------------------------------------------------------------------------
// Depthwise causal conv (width 4) + bias + SiLU; writes u (f32) and u_bf.
// ---------------------------------------------------------------------------
__global__ __launch_bounds__(256) void conv_silu_k(
    const float* __restrict__ xz, const float* __restrict__ w,
    const float* __restrict__ cb, float* __restrict__ u, short* __restrict__ ubf)
{
    int idx = blockIdx.x * 256 + threadIdx.x;
    if (idx >= MROWS * (D_INNER / 4)) return;
    int dq = idx % (D_INNER / 4);
    int m  = idx / (D_INNER / 4);
    int d0 = dq * 4;
    int b = m / L_, l = m % L_;
    float4 wq[4];
#pragma unroll
    for (int j = 0; j < 4; ++j) wq[j] = *(const float4*)(w + (d0 + j) * D_CONV);
    float acc[4];
#pragma unroll
    for (int j = 0; j < 4; ++j) acc[j] = cb[d0 + j];
#pragma unroll
    for (int tt = 0; tt < 4; ++tt) {
        int ll = l - 3 + tt;
        if (ll >= 0) {
            float4 xv = *(const float4*)(xz + (size_t)(b * L_ + ll) * (2 * D_INNER) + d0);
            acc[0] = fmaf(xv.x, ((const float*)&wq[0])[tt], acc[0]);
            acc[1] = fmaf(xv.y, ((const float*)&wq[1])[tt], acc[1]);
            acc[2] = fmaf(xv.z, ((const float*)&wq[2])[tt], acc[2]);
            acc[3] = fmaf(xv.w, ((const float*)&wq[3])[tt], acc[3]);
        }
    }
    float4 o = make_float4(silu_f(acc[0]), silu_f(acc[1]), silu_f(acc[2]), silu_f(acc[3]));
    *(float4*)(u + (size_t)m * D_INNER + d0) = o;
    uint2 pk;
    pk.x = pack2bf(o.x, o.y);
    pk.y = pack2bf(o.z, o.w);
    *(uint2*)(ubf + (size_t)m * D_INNER + d0) = pk;
}

// ---------------------------------------------------------------------------
// Chunked selective scan, pass 1 (local, h0=0): y_local, P=prod(e), H=end h.
// grid (48, NCH, B_), block = 16 d x 16 n.
// ---------------------------------------------------------------------------
__global__ __launch_bounds__(256) void scan1_k(
    const float* __restrict__ delta, const float* __restrict__ u,
    const float* __restrict__ xdbl, const float* __restrict__ A_log,
    const float* __restrict__ Dp, float* __restrict__ y,
    float* __restrict__ Pws, float* __restrict__ Hws)
{
    __shared__ float sd[SCH][16], su[SCH][16], sB[SCH][16], sC[SCH][16];
    const int t  = threadIdx.x;
    const int n  = t & 15;
    const int dl = t >> 4;
    const int dg = blockIdx.x;
    const int c  = blockIdx.y;
    const int b  = blockIdx.z;
    const int d  = dg * 16 + dl;
    const int l0 = c * SCH;

    const float Av = -expf(A_log[d * N_STATE + n]);
    const float Dd = Dp[d];
    const int lr = t >> 2;
    const int lc = (t & 3) << 2;

    {
        const size_t mrow = (size_t)b * L_ + l0 + lr;
        *(float4*)&sd[lr][lc] = *(const float4*)(delta + mrow * D_INNER + dg * 16 + lc);
        *(float4*)&su[lr][lc] = *(const float4*)(u     + mrow * D_INNER + dg * 16 + lc);
        *(float4*)&sB[lr][lc] = *(const float4*)(xdbl  + mrow * XPROJ_N + DT_RANK + lc);
        *(float4*)&sC[lr][lc] = *(const float4*)(xdbl  + mrow * XPROJ_N + DT_RANK + N_STATE + lc);
    }
    __syncthreads();

    float h = 0.f, pacc = 1.f;
#pragma unroll 8
    for (int j = 0; j < SCH; ++j) {
        float dv = sd[j][dl];
        float uv = su[j][dl];
        float e  = __expf(dv * Av);
        float cc = dv * uv * sB[j][n];
        h = fmaf(e, h, cc);
        pacc *= e;
        float p = h * sC[j][n];
        p = dpp_radd<0x128>(p);
        p = dpp_radd<0x124>(p);
        p = dpp_radd<0x122>(p);
        p = dpp_radd<0x121>(p);
        if (n == 0) y[((size_t)b * L_ + l0 + j) * D_INNER + d] = fmaf(uv, Dd, p);
    }
    const size_t phi = (((size_t)(b * NCH + c) * D_INNER + dg * 16 + dl) << 4) + n;
    Pws[phi] = pacc;
    Hws[phi] = h;
}

// ---------------------------------------------------------------------------
// Chunked selective scan, pass 2: add carry-in contribution for chunks 1..7.
// ---------------------------------------------------------------------------
__global__ __launch_bounds__(256) void scan2_k(
    const float* __restrict__ delta, const float* __restrict__ xdbl,
    const float* __restrict__ A_log,
    const float* __restrict__ Pws, const float* __restrict__ Hws,
    float* __restrict__ y)
{
    __shared__ float sd[SCH][16], sC[SCH][16];
    const int t  = threadIdx.x;
    const int n  = t & 15;
    const int dl = t >> 4;
    const int dg = blockIdx.x;
    const int c  = blockIdx.y + 1;
    const int b  = blockIdx.z;
    const int d  = dg * 16 + dl;
    const int l0 = c * SCH;

    const float Av = -expf(A_log[d * N_STATE + n]);

    float hs = 0.f;
    for (int s = 0; s < c; ++s) {
        const size_t phi = (((size_t)(b * NCH + s) * D_INNER + d) << 4) + n;
        hs = fmaf(Pws[phi], hs, Hws[phi]);
    }

    const int lr = t >> 2;
    const int lc = (t & 3) << 2;
    {
        const size_t mrow = (size_t)b * L_ + l0 + lr;
        *(float4*)&sd[lr][lc] = *(const float4*)(delta + mrow * D_INNER + dg * 16 + lc);
        *(float4*)&sC[lr][lc] = *(const float4*)(xdbl  + mrow * XPROJ_N + DT_RANK + N_STATE + lc);
    }
    __syncthreads();

    float g = hs;
#pragma unroll 8
    for (int j = 0; j < SCH; ++j) {
        float dv = sd[j][dl];
        g *= __expf(dv * Av);
        float p = g * sC[j][n];
        p = dpp_radd<0x128>(p);
        p = dpp_radd<0x124>(p);
        p = dpp_radd<0x122>(p);
        p = dpp_radd<0x121>(p);
        if (n == 0) y[((size_t)b * L_ + l0 + j) * D_INNER + d] += p;
    }
}

// ---------------------------------------------------------------------------
extern "C" void kernel_launch(void* const* d_in, const int* in_sizes, int n_in,
                              void* d_out, int out_size, void* d_ws, size_t ws_size,
                              hipStream_t stream)
{
    const float* input_ids = (const float*)d_in[0];
    const float* fc_W      = (const float*)d_in[1];
    const float* fc_b      = (const float*)d_in[2];
    const float* in_proj_W = (const float*)d_in[3];
    const float* conv_W    = (const float*)d_in[4];
    const float* conv_b    = (const float*)d_in[5];
    const float* x_proj_W  = (const float*)d_in[6];
    const float* dt_proj_W = (const float*)d_in[7];
    const float* dt_proj_b = (const float*)d_in[8];
    const float* A_log     = (const float*)d_in[9];
    const float* Dp        = (const float*)d_in[10];
    const float* out_proj_W= (const float*)d_in[11];
    const float* norm_W    = (const float*)d_in[12];
    const float* normf_W   = (const float*)d_in[13];
    const float* head_W    = (const float*)d_in[14];
    float* out = (float*)d_out;

    float* ws       = (float*)d_ws;
    float* x_ws     = ws;                                    // M*384
    float* xz_ws    = x_ws    + (size_t)MROWS * D_MODEL;     // M*1536
    float* u_ws     = xz_ws   + (size_t)MROWS * 2 * D_INNER; // M*768
    float* xdbl_ws  = u_ws    + (size_t)MROWS * D_INNER;     // M*56
    float* delta_ws = xdbl_ws + (size_t)MROWS * XPROJ_N;     // M*768
    float* y_ws     = delta_ws+ (size_t)MROWS * D_INNER;     // M*768
    float* P_ws     = y_ws    + (size_t)MROWS * D_INNER;     // B*8*768*16
    float* H_ws     = P_ws    + (size_t)B_ * NCH * D_INNER * N_STATE;
    short* bf       = (short*)(H_ws + (size_t)B_ * NCH * D_INNER * N_STATE);
    short* wbf_fc   = bf;
    short* wbf_in   = wbf_fc  + (size_t)D_MODEL * VOCAB;
    short* wbf_x    = wbf_in  + (size_t)N_LAYER * 2 * D_INNER * D_MODEL;
    short* wbf_dt   = wbf_x   + (size_t)N_LAYER * XPROJ_N * D_INNER;
    short* wbf_out  = wbf_dt  + (size_t)N_LAYER * D_INNER * DT_RANK;
    short* wbf_head = wbf_out + (size_t)N_LAYER * D_MODEL * D_INNER;
    short* ubf_ws   = wbf_head+ (size_t)FEAT * D_MODEL;

    const dim3 blk(256);

    // --- one-shot weight cast to bf16 ---
    CastDesc cd;
    cd.src[0] = fc_W;       cd.dst[0] = wbf_fc;
    cd.src[1] = in_proj_W;  cd.dst[1] = wbf_in;
    cd.src[2] = x_proj_W;   cd.dst[2] = wbf_x;
    cd.src[3] = dt_proj_W;  cd.dst[3] = wbf_dt;
    cd.src[4] = out_proj_W; cd.dst[4] = wbf_out;
    cd.src[5] = head_W;     cd.dst[5] = wbf_head;
    unsigned c0 = (unsigned)(D_MODEL * VOCAB / 4);
    unsigned c1 = c0 + (unsigned)(N_LAYER * 2 * D_INNER * D_MODEL / 4);
    unsigned c2 = c1 + (unsigned)(N_LAYER * XPROJ_N * D_INNER / 4);
    unsigned c3 = c2 + (unsigned)(N_LAYER * D_INNER * DT_RANK / 4);
    unsigned c4 = c3 + (unsigned)(N_LAYER * D_MODEL * D_INNER / 4);
    unsigned c5 = c4 + (unsigned)(FEAT * D_MODEL / 4);
    cd.cum[0] = c0; cd.cum[1] = c1; cd.cum[2] = c2;
    cd.cum[3] = c3; cd.cum[4] = c4; cd.cum[5] = c5;
    cast_w_k<<<(c5 + 255) / 256, blk, 0, stream>>>(cd, c5);

    // x = input_ids @ fc_W.T + fc_b   (split-K=7, KC=256)
    hipMemsetAsync(x_ws, 0, (size_t)MROWS * D_MODEL * sizeof(float), stream);
    mfma_gemm<1, false, true, false, false, false><<<dim3(D_MODEL / 64, MROWS / 64, 7), blk, 0, stream>>>(
        input_ids, nullptr, wbf_fc, fc_b, nullptr, nullptr, x_ws,
        MROWS, D_MODEL, VOCAB, VOCAB, 0, D_MODEL, 256);

    for (int i = 0; i < N_LAYER; ++i) {
        // xz = rmsnorm(x, norm_W) @ in_proj_W.T   (rmsnorm fused into A staging)
        mfma_gemm<0, false, false, true, false, false><<<dim3(2 * D_INNER / 64, MROWS / 64, 1), blk, 0, stream>>>(
            x_ws, nullptr, wbf_in + (size_t)i * 2 * D_INNER * D_MODEL,
            nullptr, nullptr, norm_W + i * D_MODEL, xz_ws,
            MROWS, 2 * D_INNER, D_MODEL, D_MODEL, 0, 2 * D_INNER, D_MODEL);

        // u = silu(conv(xz[:, :768]) + conv_b)  (f32 + bf16 copies)
        conv_silu_k<<<(MROWS * (D_INNER / 4) + 255) / 256, blk, 0, stream>>>(
            xz_ws, conv_W + (size_t)i * D_INNER * D_CONV, conv_b + i * D_INNER,
            u_ws, ubf_ws);

        // x_dbl = u @ x_proj_W[i].T  (split-K=12 -> 384 blocks)
        hipMemsetAsync(xdbl_ws, 0, (size_t)MROWS * XPROJ_N * sizeof(float), stream);
        mfma_gemm<0, false, true, false, true, true><<<dim3(1, MROWS / 64, 12), blk, 0, stream>>>(
            nullptr, ubf_ws, wbf_x + (size_t)i * XPROJ_N * D_INNER,
            nullptr, nullptr, nullptr, xdbl_ws,
            MROWS, XPROJ_N, D_INNER, D_INNER, 0, XPROJ_N, 64);

        // delta = softplus(x_dbl[:, :24] @ dt_proj_W[i].T + dt_proj_b[i])  (1 k-iter)
        mfma_gemm<2, false, false, false, false, false><<<dim3(D_INNER / 64, MROWS / 64, 1), blk, 0, stream>>>(
            xdbl_ws, nullptr, wbf_dt + (size_t)i * D_INNER * DT_RANK,
            dt_proj_b + i * D_INNER, nullptr, nullptr, delta_ws,
            MROWS, D_INNER, DT_RANK, XPROJ_N, 0, D_INNER, DT_RANK);

        // chunked selective scan (two-pass: kernel boundary is the cheap sync)
        scan1_k<<<dim3(D_INNER / 16, NCH, B_), blk, 0, stream>>>(
            delta_ws, u_ws, xdbl_ws, A_log + (size_t)i * D_INNER * N_STATE,
            Dp + i * D_INNER, y_ws, P_ws, H_ws);
        scan2_k<<<dim3(D_INNER / 16, NCH - 1, B_), blk, 0, stream>>>(
            delta_ws, xdbl_ws, A_log + (size_t)i * D_INNER * N_STATE,
            P_ws, H_ws, y_ws);

        // x += (y * silu(res)) @ out_proj_W.T  (gated A, split-K=3, atomic residual)
        mfma_gemm<0, true, true, false, false, false><<<dim3(D_MODEL / 64, MROWS / 64, 3), blk, 0, stream>>>(
            y_ws, nullptr, wbf_out + (size_t)i * D_MODEL * D_INNER,
            nullptr, xz_ws + D_INNER, nullptr, x_ws,
            MROWS, D_MODEL, D_INNER, D_INNER, 2 * D_INNER, D_MODEL, 256);
    }

    // out = rmsnorm(x, normf_W) @ head_W.T  (rmsnorm fused)
    mfma_gemm<0, false, false, true, false, false><<<dim3(FEAT / 64, MROWS / 64, 1), blk, 0, stream>>>(
        x_ws, nullptr, wbf_head, nullptr, nullptr, normf_W, out,
        MROWS, FEAT, D_MODEL, D_MODEL, 0, FEAT, D_MODEL);
}